// Round 3
// baseline (957.095 us; speedup 1.0000x reference)
//
#include <hip/hip_runtime.h>
#include <stdint.h>

// Block-major radix binning: payload region of block i is [i*chunk, i*chunk+cnt_i)
// (known a priori from chunk boundaries -> no global scan). Internal order by
// bucket via block-local LDS scan. Kills the 6.7x cross-XCD partial-line write
// amplification seen in round 2 (447 MB written for a 67 MB payload).
//
// bucket = (dt*2+p)*300 + pos   (2400 buckets)
// payload u32 = (tok << 24) | 24-bit fixed-point wt   (same as round 2, passed)

#define TPB 256
#define B1 1024
#define NBUCKET 2400
#define MAXCHUNK 16384     // chunk must fit u16 prefixes and the L2 re-read window

// ws layout (bytes): [ payload u32 * n | pfx u16 [B1][NBUCKET] | offs_t u16 [NBUCKET][B1] ]
__device__ __forceinline__ void classify(const float4 e, const float t0,
                                         const float d_wt, const float d_dt,
                                         int& bucket, int& tok, float& wt) {
    const float c1 = (float)(319.0 / 20.0 + 1e-4);   // W/PW + B
    const float c2 = (float)(239.0 / 15.0 + 1e-4);   // H/PH + B
    const int pos = (int)(floorf(e.y / c1) + floorf(e.z / c2) * 20.0f);
    tok = (int)(floorf(fmodf(e.y, c1)) + floorf(fmodf(e.z, c2)) * 16.0f);
    const int dt = (int)floorf(4.0f * (e.x - t0) / d_dt);
    const int p  = (int)e.w;
    bucket = (dt * 2 + p) * 300 + pos;
    wt = (e.x - t0) / d_wt;
}

// One pass over input: count -> LDS scan -> re-read chunk (L2/L3-warm) -> ranked
// payload write into the block's private contiguous region.
__global__ __launch_bounds__(TPB) void k_bin(const float4* __restrict__ x,
                                             uint32_t* __restrict__ payload,
                                             uint16_t* __restrict__ pfx,
                                             int n, int chunk) {
    __shared__ uint32_t cnt[NBUCKET];       // counts, then cursors
    __shared__ uint32_t wsum[TPB / 64];
    for (int i = threadIdx.x; i < NBUCKET; i += TPB) cnt[i] = 0;
    __syncthreads();

    const float* xf = (const float*)x;
    const float t0 = xf[0];
    const float tlast = xf[(size_t)(n - 1) * 4];
    const float d_wt = tlast - t0 + 1e-4f;
    const float d_dt = tlast - t0 + 1.0f;

    const int beg = blockIdx.x * chunk;
    const int end = min(beg + chunk, n);

    // phase 1: count
    for (int i = beg + threadIdx.x; i < end; i += TPB) {
        float4 e = x[i];
        int bucket, tok; float wt;
        classify(e, t0, d_wt, d_dt, bucket, tok, wt);
        atomicAdd(&cnt[bucket], 1u);
    }
    __syncthreads();

    // phase 2: block-local exclusive scan of 2400 counts (10 per thread)
    uint32_t v[10];
    uint32_t sum = 0;
    const int base_i = threadIdx.x * 10;
    #pragma unroll
    for (int j = 0; j < 10; ++j) {
        int idx = base_i + j;
        uint32_t c = (idx < NBUCKET) ? cnt[idx] : 0u;
        v[j] = sum;                    // local exclusive prefix
        sum += c;
    }
    uint32_t inc = sum;
    #pragma unroll
    for (int off = 1; off < 64; off <<= 1) {
        uint32_t u = __shfl_up(inc, off, 64);
        if ((threadIdx.x & 63) >= off) inc += u;
    }
    const int wid = threadIdx.x >> 6, lid = threadIdx.x & 63;
    if (lid == 63) wsum[wid] = inc;
    __syncthreads();
    uint32_t woff = 0;
    for (int w = 0; w < wid; ++w) woff += wsum[w];
    const uint32_t excl = woff + inc - sum;

    uint16_t* prow = pfx + (size_t)blockIdx.x * NBUCKET;
    #pragma unroll
    for (int j = 0; j < 10; ++j) {
        int idx = base_i + j;
        if (idx < NBUCKET) {
            uint32_t p = excl + v[j];
            cnt[idx] = p;              // cursor
            prow[idx] = (uint16_t)p;   // coalesced-ish segment-start write
        }
    }
    __syncthreads();

    // phase 3: re-read chunk (just-read -> L2/L3 hit), rank, write payload
    uint32_t* pbase = payload + (size_t)blockIdx.x * chunk;
    for (int i = beg + threadIdx.x; i < end; i += TPB) {
        float4 e = x[i];
        int bucket, tok; float wt;
        classify(e, t0, d_wt, d_dt, bucket, tok, wt);
        uint32_t q = (uint32_t)(wt * 16777216.0f);
        q = q > 16777215u ? 16777215u : q;
        uint32_t rank = atomicAdd(&cnt[bucket], 1u);
        pbase[rank] = ((uint32_t)tok << 24) | q;   // 4B store inside private 64KB window
    }
}

// pfx [B1][NBUCKET] u16  ->  offs_t [NBUCKET][B1] u16 (so k_accum reads coalesced)
__global__ __launch_bounds__(256) void k_transpose(const uint16_t* __restrict__ in,
                                                   uint16_t* __restrict__ out) {
    __shared__ uint16_t tile[32][33];
    const int b0 = blockIdx.x * 32;    // bucket tile (2400/32 = 75)
    const int r0 = blockIdx.y * 32;    // block tile  (1024/32 = 32)
    const int tx = threadIdx.x & 31;
    const int ty = threadIdx.x >> 5;   // 0..7
    for (int j = ty; j < 32; j += 8)
        tile[j][tx] = in[(size_t)(r0 + j) * NBUCKET + (b0 + tx)];
    __syncthreads();
    for (int j = ty; j < 32; j += 8)
        out[(size_t)(b0 + j) * B1 + (r0 + tx)] = tile[tx][j];
}

// One block per bucket: gather its 1024 segments, LDS fp-atomic histogram,
// write 512 outputs exactly once.
__global__ __launch_bounds__(TPB) void k_accum(const uint32_t* __restrict__ payload,
                                               const uint16_t* __restrict__ offs_t,
                                               float* __restrict__ out,
                                               int n, int chunk) {
    __shared__ float hist[512];
    __shared__ uint16_t sbeg[B1], send[B1];
    hist[threadIdx.x] = 0.0f;
    hist[threadIdx.x + 256] = 0.0f;
    const int b = blockIdx.x;
    const uint16_t* row0 = offs_t + (size_t)b * B1;
    for (int i = threadIdx.x; i < B1; i += TPB) {
        sbeg[i] = row0[i];
        if (b + 1 < NBUCKET) {
            send[i] = offs_t[(size_t)(b + 1) * B1 + i];
        } else {
            int c = n - i * chunk;
            c = c < 0 ? 0 : (c > chunk ? chunk : c);
            send[i] = (uint16_t)c;     // last bucket ends at the block's event count
        }
    }
    __syncthreads();
    for (int blk = threadIdx.x; blk < B1; blk += TPB) {
        const uint32_t* seg = payload + (size_t)blk * chunk;
        const int e = send[blk];
        for (int j = sbeg[blk]; j < e; ++j) {
            uint32_t w = seg[j];                       // per-lane line walk, L1-resident
            int tok = w >> 24;
            float wt = (float)(w & 0xFFFFFFu) * (1.0f / 16777216.0f);
            atomicAdd(&hist[tok], 1.0f);
            atomicAdd(&hist[256 + tok], wt);
        }
    }
    __syncthreads();
    // b = (dt*2+p)*300 + pos; out = (dt*2+p)*153600 + c*76800 + tok*300 + pos
    const int pos = b % 300;
    const int dp = b / 300;
    const int base0 = dp * 153600 + pos;
    out[base0 + threadIdx.x * 300]         = hist[threadIdx.x];
    out[base0 + 76800 + threadIdx.x * 300] = hist[256 + threadIdx.x];
}

// ---- fallback (ws too small / n too large for u16 prefixes) ----
__global__ __launch_bounds__(TPB) void e2src_hist_atomic(const float4* __restrict__ x,
                                                         float* __restrict__ out, int n) {
    const float* xf = (const float*)x;
    const float t0 = xf[0];
    const float tlast = xf[(size_t)(n - 1) * 4];
    const float d_wt = tlast - t0 + 1e-4f;
    const float d_dt = tlast - t0 + 1.0f;
    int i = blockIdx.x * blockDim.x + threadIdx.x;
    const int stride = gridDim.x * blockDim.x;
    for (; i < n; i += stride) {
        float4 e = x[i];
        int bucket, tok; float wt;
        classify(e, t0, d_wt, d_dt, bucket, tok, wt);
        const int dp = bucket / 300, pos = bucket % 300;
        const int base = dp * 153600 + tok * 300 + pos;
        unsafeAtomicAdd(out + base, 1.0f);
        unsafeAtomicAdd(out + base + 76800, wt);
    }
}

extern "C" void kernel_launch(void* const* d_in, const int* in_sizes, int n_in,
                              void* d_out, int out_size, void* d_ws, size_t ws_size,
                              hipStream_t stream) {
    const float* x = (const float*)d_in[0];
    float* out = (float*)d_out;
    const int n = in_sizes[0] / 4;
    const int chunk = (n + B1 - 1) / B1;

    const size_t payload_bytes = (size_t)n * 4u;
    const size_t pfx_bytes = (size_t)B1 * NBUCKET * 2u;
    const size_t need = payload_bytes + 2u * pfx_bytes;    // 76.94 MB at n=16.7M

    if (ws_size < need || chunk > MAXCHUNK) {
        hipMemsetAsync(d_out, 0, (size_t)out_size * sizeof(float), stream);
        hipLaunchKernelGGL(e2src_hist_atomic, dim3(8192), dim3(TPB), 0, stream,
                           (const float4*)x, out, n);
        return;
    }

    uint32_t* payload = (uint32_t*)d_ws;
    uint16_t* pfx    = (uint16_t*)((char*)d_ws + payload_bytes);
    uint16_t* offs_t = (uint16_t*)((char*)d_ws + payload_bytes + pfx_bytes);

    hipLaunchKernelGGL(k_bin, dim3(B1), dim3(TPB), 0, stream,
                       (const float4*)x, payload, pfx, n, chunk);
    hipLaunchKernelGGL(k_transpose, dim3(NBUCKET / 32, B1 / 32), dim3(256), 0, stream,
                       pfx, offs_t);
    hipLaunchKernelGGL(k_accum, dim3(NBUCKET), dim3(TPB), 0, stream,
                       payload, offs_t, out, n, chunk);
    // k_accum writes all outputs exactly once -> no memset needed.
}

// Round 4
// 650.206 us; speedup vs baseline: 1.4720x; 1.4720x over previous
//
#include <hip/hip_runtime.h>
#include <stdint.h>

// Round 4: complete cache lines in LDS before they hit memory.
// k_bin: count -> LDS scan -> re-read chunk (L2-warm) -> bucket-sorted payload
//        staged in DYNAMIC LDS -> coalesced uint4 writeout (kills the 472 MB
//        partial-line write amplification measured in rounds 2 & 3).
// k_accum: per-bucket block; gathers per-(block,bucket) segments; ONE packed
//        ds_add_u64 per event: (count:24 @ bit40 | wt fixed-point:24 @ bit0).
//
// bucket = (dt*2+p)*300 + pos   (2400 buckets)
// payload u32 = (tok << 24) | 24-bit fixed-point wt   (validated rounds 2-3)

#define TPB 256
#define B1 2048            // k_bin blocks; chunk = ceil(n/B1) = 8192 at n=2^24
#define NBUCKET 2400
#define SCAN_PER 10        // ceil(NBUCKET / TPB)

// ws layout (bytes): [ payload u32 * n | pfx u16 [B1][NBUCKET] ]  = 76.94 MB

__device__ __forceinline__ int classify_bucket(const float4 e, const float t0,
                                               const float d_dt) {
    const float c1 = (float)(319.0 / 20.0 + 1e-4);   // W/PW + B
    const float c2 = (float)(239.0 / 15.0 + 1e-4);   // H/PH + B
    const int pos = (int)(floorf(e.y / c1) + floorf(e.z / c2) * 20.0f);
    const int dt  = (int)floorf(4.0f * (e.x - t0) / d_dt);
    const int p   = (int)e.w;
    return (dt * 2 + p) * 300 + pos;
}

__device__ __forceinline__ void classify_full(const float4 e, const float t0,
                                              const float d_wt, const float d_dt,
                                              int& bucket, int& tok, float& wt) {
    const float c1 = (float)(319.0 / 20.0 + 1e-4);
    const float c2 = (float)(239.0 / 15.0 + 1e-4);
    const int pos = (int)(floorf(e.y / c1) + floorf(e.z / c2) * 20.0f);
    tok = (int)(floorf(fmodf(e.y, c1)) + floorf(fmodf(e.z, c2)) * 16.0f);
    const int dt = (int)floorf(4.0f * (e.x - t0) / d_dt);
    const int p  = (int)e.w;
    bucket = (dt * 2 + p) * 300 + pos;
    wt = (e.x - t0) / d_wt;
}

__global__ __launch_bounds__(TPB) void k_bin(const float4* __restrict__ x,
                                             uint32_t* __restrict__ payload,
                                             uint16_t* __restrict__ pfx,
                                             int n, int chunk) {
    extern __shared__ uint32_t smem[];   // [chunk] stage | [NBUCKET] cnt
    uint32_t* stage = smem;
    uint32_t* cnt = smem + chunk;
    __shared__ uint32_t wsum[TPB / 64];

    for (int i = threadIdx.x; i < NBUCKET; i += TPB) cnt[i] = 0;
    __syncthreads();

    const float* xf = (const float*)x;
    const float t0 = xf[0];
    const float tlast = xf[(size_t)(n - 1) * 4];
    const float d_wt = tlast - t0 + 1e-4f;
    const float d_dt = tlast - t0 + 1.0f;

    const int beg = blockIdx.x * chunk;
    const int end = min(beg + chunk, n);

    // phase 1: count (only bucket needed; tok/wt dead-code-eliminated)
    for (int i = beg + threadIdx.x; i < end; i += TPB) {
        float4 e = x[i];
        atomicAdd(&cnt[classify_bucket(e, t0, d_dt)], 1u);
    }
    __syncthreads();

    // phase 2: block-local exclusive scan of NBUCKET counts
    uint32_t v[SCAN_PER];
    uint32_t sum = 0;
    const int base_i = threadIdx.x * SCAN_PER;
    #pragma unroll
    for (int j = 0; j < SCAN_PER; ++j) {
        int idx = base_i + j;
        uint32_t c = (idx < NBUCKET) ? cnt[idx] : 0u;
        v[j] = sum;                     // local exclusive prefix
        sum += c;
    }
    uint32_t inc = sum;
    #pragma unroll
    for (int off = 1; off < 64; off <<= 1) {
        uint32_t u = __shfl_up(inc, off, 64);
        if ((threadIdx.x & 63) >= off) inc += u;
    }
    const int wid = threadIdx.x >> 6, lid = threadIdx.x & 63;
    if (lid == 63) wsum[wid] = inc;
    __syncthreads();
    uint32_t woff = 0;
    for (int w = 0; w < wid; ++w) woff += wsum[w];
    const uint32_t excl = woff + inc - sum;

    uint16_t* prow = pfx + (size_t)blockIdx.x * NBUCKET;
    #pragma unroll
    for (int j = 0; j < SCAN_PER; ++j) {
        int idx = base_i + j;
        if (idx < NBUCKET) {
            uint32_t p = excl + v[j];
            cnt[idx] = p;               // cursor
            prow[idx] = (uint16_t)p;    // segment start, block-major
        }
    }
    __syncthreads();

    // phase 3: re-read chunk (L2-warm), rank, scatter INTO LDS stage
    for (int i = beg + threadIdx.x; i < end; i += TPB) {
        float4 e = x[i];
        int bucket, tok; float wt;
        classify_full(e, t0, d_wt, d_dt, bucket, tok, wt);
        uint32_t q = (uint32_t)(wt * 16777216.0f);
        q = q > 16777215u ? 16777215u : q;
        uint32_t rank = atomicAdd(&cnt[bucket], 1u);
        stage[rank] = ((uint32_t)tok << 24) | q;
    }
    __syncthreads();

    // phase 4: coalesced LDS -> global writeout (complete lines only)
    const int cntE = end - beg;
    uint32_t* pbase = payload + (size_t)blockIdx.x * chunk;
    const int n4 = cntE >> 2;
    const uint4* s4 = (const uint4*)stage;
    uint4* g4 = (uint4*)pbase;
    for (int i = threadIdx.x; i < n4; i += TPB) g4[i] = s4[i];
    for (int i = (n4 << 2) + threadIdx.x; i < cntE; i += TPB) pbase[i] = stage[i];
}

// One block per bucket. Reads pfx block-major (gathers, L2/L3-served: 10 MB
// total). One packed u64 LDS atomic per event.
__global__ __launch_bounds__(TPB) void k_accum(const uint32_t* __restrict__ payload,
                                               const uint16_t* __restrict__ pfx,
                                               float* __restrict__ out,
                                               int n, int chunk) {
    __shared__ unsigned long long hist[256];   // tok -> (count<<40 | wt_q24_sum)
    hist[threadIdx.x] = 0ULL;
    __syncthreads();
    const int b = blockIdx.x;
    for (int i = threadIdx.x; i < B1; i += TPB) {
        const uint16_t* prow = pfx + (size_t)i * NBUCKET;
        const int sbeg = prow[b];
        int send;
        if (b + 1 < NBUCKET) {
            send = prow[b + 1];
        } else {
            int c = n - i * chunk;
            send = c < 0 ? 0 : (c > chunk ? chunk : c);
        }
        const uint32_t* seg = payload + (size_t)i * chunk;
        for (int j = sbeg; j < send; ++j) {
            uint32_t w = seg[j];
            // count in bits [40,64), wt fixed-point sum in bits [0,40).
            // bin count ~27 avg -> wt sum < 2^31 << 2^40: no carry into count.
            atomicAdd(&hist[w >> 24],
                      (1ULL << 40) | (unsigned long long)(w & 0xFFFFFFu));
        }
    }
    __syncthreads();
    const unsigned long long v = hist[threadIdx.x];
    const float cntf = (float)(uint32_t)(v >> 40);
    const float wts  = (float)(v & ((1ULL << 40) - 1)) * (1.0f / 16777216.0f);
    // b = (dt*2+p)*300 + pos; out = (dt*2+p)*153600 + c*76800 + tok*300 + pos
    const int pos = b % 300;
    const int dp = b / 300;
    const int base0 = dp * 153600 + pos;
    out[base0 + threadIdx.x * 300]         = cntf;   // c=0: count
    out[base0 + 76800 + threadIdx.x * 300] = wts;    // c=1: wt sum
}

// ---- fallback (ws too small / chunk out of range) ----
__global__ __launch_bounds__(TPB) void e2src_hist_atomic(const float4* __restrict__ x,
                                                         float* __restrict__ out, int n) {
    const float* xf = (const float*)x;
    const float t0 = xf[0];
    const float tlast = xf[(size_t)(n - 1) * 4];
    const float d_wt = tlast - t0 + 1e-4f;
    const float d_dt = tlast - t0 + 1.0f;
    int i = blockIdx.x * blockDim.x + threadIdx.x;
    const int stride = gridDim.x * blockDim.x;
    for (; i < n; i += stride) {
        float4 e = x[i];
        int bucket, tok; float wt;
        classify_full(e, t0, d_wt, d_dt, bucket, tok, wt);
        const int dp = bucket / 300, pos = bucket % 300;
        const int base = dp * 153600 + tok * 300 + pos;
        unsafeAtomicAdd(out + base, 1.0f);
        unsafeAtomicAdd(out + base + 76800, wt);
    }
}

extern "C" void kernel_launch(void* const* d_in, const int* in_sizes, int n_in,
                              void* d_out, int out_size, void* d_ws, size_t ws_size,
                              hipStream_t stream) {
    const float* x = (const float*)d_in[0];
    float* out = (float*)d_out;
    const int n = in_sizes[0] / 4;
    const int chunk = (n + B1 - 1) / B1;

    const size_t payload_bytes = (size_t)n * 4u;
    const size_t pfx_bytes = (size_t)B1 * NBUCKET * 2u;
    const size_t need = payload_bytes + pfx_bytes;          // 76.94 MB at n=2^24
    const size_t lds_bytes = ((size_t)chunk + NBUCKET) * 4u; // 42.4 KB at chunk=8192

    if (ws_size < need || chunk > 65535 || lds_bytes > 65536) {
        hipMemsetAsync(d_out, 0, (size_t)out_size * sizeof(float), stream);
        hipLaunchKernelGGL(e2src_hist_atomic, dim3(8192), dim3(TPB), 0, stream,
                           (const float4*)x, out, n);
        return;
    }

    uint32_t* payload = (uint32_t*)d_ws;
    uint16_t* pfx = (uint16_t*)((char*)d_ws + payload_bytes);

    hipLaunchKernelGGL(k_bin, dim3(B1), dim3(TPB), lds_bytes, stream,
                       (const float4*)x, payload, pfx, n, chunk);
    hipLaunchKernelGGL(k_accum, dim3(NBUCKET), dim3(TPB), 0, stream,
                       payload, pfx, out, n, chunk);
    // k_accum writes every output exactly once -> no memset needed.
}

// Round 5
// 543.147 us; speedup vs baseline: 1.7621x; 1.1971x over previous
//
#include <hip/hip_runtime.h>
#include <stdint.h>

// Round 5:
//  k_bin: classify ONCE per event (register stash of 32 payload+bucket pairs
//         per thread), LDS scan, LDS-staged bucket sort, coalesced uint4
//         writeout. Numerics identical to rounds 2-4 (passing).
//  k_accum: G=4 adjacent buckets per block (600 blocks) -> per-chunk read span
//         ~54 B contiguous instead of 4 scattered 13.6 B segments; XCD-swizzled
//         block->bucket mapping so adjacent buckets share an XCD L2 (kills the
//         cross-XCD duplicate line fetch behind the measured 551 MB FETCH).
//  Packed u64 LDS atomic per event: (count @ bit40 | wt q24 sum @ bit0).
//
// bucket = (dt*2+p)*300 + pos  (2400); payload u32 = (tok<<24) | wt_q24.

#define TPB 256
#define B1 2048
#define CHUNK 8192                 // B1*CHUNK = 2^24 = n
#define EVT (CHUNK / TPB)          // 32 events per thread
#define NBUCKET 2400
#define SCAN_PER 10                // ceil(NBUCKET/TPB)
#define GACC 4                     // buckets per k_accum block
#define NACC (NBUCKET / GACC)      // 600 blocks

// ws layout (bytes): [ payload u32 * n | pfx u16 [B1][NBUCKET] ] = 76.94 MB

__device__ __forceinline__ void classify_full(const float4 e, const float t0,
                                              const float d_wt, const float d_dt,
                                              int& bucket, int& tok, float& wt) {
    const float c1 = (float)(319.0 / 20.0 + 1e-4);   // W/PW + B
    const float c2 = (float)(239.0 / 15.0 + 1e-4);   // H/PH + B
    const int pos = (int)(floorf(e.y / c1) + floorf(e.z / c2) * 20.0f);
    tok = (int)(floorf(fmodf(e.y, c1)) + floorf(fmodf(e.z, c2)) * 16.0f);
    const int dt = (int)floorf(4.0f * (e.x - t0) / d_dt);
    const int p  = (int)e.w;
    bucket = (dt * 2 + p) * 300 + pos;
    wt = (e.x - t0) / d_wt;
}

__global__ __launch_bounds__(TPB, 3) void k_bin(const float4* __restrict__ x,
                                                uint32_t* __restrict__ payload,
                                                uint16_t* __restrict__ pfx,
                                                int n) {
    __shared__ uint32_t stage[CHUNK];     // 32 KB
    __shared__ uint32_t cnt[NBUCKET];     // 9.6 KB: counts, then cursors
    __shared__ uint32_t wsum[TPB / 64];

    for (int i = threadIdx.x; i < NBUCKET; i += TPB) cnt[i] = 0;
    __syncthreads();

    const float* xf = (const float*)x;
    const float t0 = xf[0];
    const float tlast = xf[(size_t)(n - 1) * 4];
    const float d_wt = tlast - t0 + 1e-4f;
    const float d_dt = tlast - t0 + 1.0f;

    const int beg = blockIdx.x * CHUNK;
    const bool full = (beg + CHUNK <= n);

    // phase 1: classify once, stash in registers, count
    uint32_t pk[EVT];
    uint32_t bk[EVT];
    if (full) {
        #pragma unroll
        for (int k = 0; k < EVT; ++k) {
            float4 e = x[beg + threadIdx.x + k * TPB];
            int bucket, tok; float wt;
            classify_full(e, t0, d_wt, d_dt, bucket, tok, wt);
            uint32_t q = (uint32_t)(wt * 16777216.0f);
            q = q > 16777215u ? 16777215u : q;
            pk[k] = ((uint32_t)tok << 24) | q;
            bk[k] = (uint32_t)bucket;
            atomicAdd(&cnt[bucket], 1u);
        }
    } else {
        #pragma unroll
        for (int k = 0; k < EVT; ++k) {
            const int i = beg + threadIdx.x + k * TPB;
            if (i < n) {
                float4 e = x[i];
                int bucket, tok; float wt;
                classify_full(e, t0, d_wt, d_dt, bucket, tok, wt);
                uint32_t q = (uint32_t)(wt * 16777216.0f);
                q = q > 16777215u ? 16777215u : q;
                pk[k] = ((uint32_t)tok << 24) | q;
                bk[k] = (uint32_t)bucket;
                atomicAdd(&cnt[bucket], 1u);
            } else {
                bk[k] = 0xFFFFFFFFu;
            }
        }
    }
    __syncthreads();

    // phase 2: block-local exclusive scan of NBUCKET counts
    uint32_t v[SCAN_PER];
    uint32_t sum = 0;
    const int base_i = threadIdx.x * SCAN_PER;
    #pragma unroll
    for (int j = 0; j < SCAN_PER; ++j) {
        int idx = base_i + j;
        uint32_t c = (idx < NBUCKET) ? cnt[idx] : 0u;
        v[j] = sum;
        sum += c;
    }
    uint32_t inc = sum;
    #pragma unroll
    for (int off = 1; off < 64; off <<= 1) {
        uint32_t u = __shfl_up(inc, off, 64);
        if ((threadIdx.x & 63) >= off) inc += u;
    }
    const int wid = threadIdx.x >> 6, lid = threadIdx.x & 63;
    if (lid == 63) wsum[wid] = inc;
    __syncthreads();
    uint32_t woff = 0;
    for (int w = 0; w < wid; ++w) woff += wsum[w];
    const uint32_t excl = woff + inc - sum;

    uint16_t* prow = pfx + (size_t)blockIdx.x * NBUCKET;
    #pragma unroll
    for (int j = 0; j < SCAN_PER; ++j) {
        int idx = base_i + j;
        if (idx < NBUCKET) {
            uint32_t p = excl + v[j];
            cnt[idx] = p;               // cursor
            prow[idx] = (uint16_t)p;    // segment start
        }
    }
    __syncthreads();

    // phase 3: replay from registers -> rank -> LDS stage
    if (full) {
        #pragma unroll
        for (int k = 0; k < EVT; ++k) {
            uint32_t rank = atomicAdd(&cnt[bk[k]], 1u);
            stage[rank] = pk[k];
        }
    } else {
        #pragma unroll
        for (int k = 0; k < EVT; ++k) {
            if (bk[k] != 0xFFFFFFFFu) {
                uint32_t rank = atomicAdd(&cnt[bk[k]], 1u);
                stage[rank] = pk[k];
            }
        }
    }
    __syncthreads();

    // phase 4: coalesced LDS -> global writeout (complete lines only)
    const int end = min(beg + CHUNK, n);
    const int cntE = end - beg;
    uint32_t* pbase = payload + (size_t)blockIdx.x * CHUNK;
    const int n4 = cntE >> 2;
    const uint4* s4 = (const uint4*)stage;
    uint4* g4 = (uint4*)pbase;
    for (int i = threadIdx.x; i < n4; i += TPB) g4[i] = s4[i];
    for (int i = (n4 << 2) + threadIdx.x; i < cntE; i += TPB) pbase[i] = stage[i];
}

// One block per 4 ADJACENT buckets, XCD-swizzled so XCD k owns buckets
// [300k, 300k+300): shared payload/pfx lines stay in one XCD's L2.
__global__ __launch_bounds__(TPB) void k_accum(const uint32_t* __restrict__ payload,
                                               const uint16_t* __restrict__ pfx,
                                               float* __restrict__ out,
                                               int n) {
    __shared__ unsigned long long hist[GACC * 256];   // (c,tok) -> count<<40 | wt_q24
    for (int i = threadIdx.x; i < GACC * 256; i += TPB) hist[i] = 0ULL;
    __syncthreads();

    const int xcd = blockIdx.x & 7;
    const int slot = blockIdx.x >> 3;
    const int g = xcd * (NACC / 8) + slot;    // 75 groups per XCD
    const int b0 = g * GACC;

    for (int row = threadIdx.x; row < B1; row += TPB) {
        const uint16_t* prow = pfx + (size_t)row * NBUCKET + b0;
        int off[GACC + 1];
        #pragma unroll
        for (int c = 0; c < GACC; ++c) off[c] = prow[c];
        if (b0 + GACC < NBUCKET) {
            off[GACC] = prow[GACC];
        } else {
            int rc = n - row * CHUNK;
            off[GACC] = rc < 0 ? 0 : (rc > CHUNK ? CHUNK : rc);
        }
        const uint32_t* seg = payload + (size_t)row * CHUNK;
        #pragma unroll
        for (int c = 0; c < GACC; ++c) {
            for (int j = off[c]; j < off[c + 1]; ++j) {
                uint32_t w = seg[j];     // ~54 B contiguous span per row
                atomicAdd(&hist[(c << 8) | (w >> 24)],
                          (1ULL << 40) | (unsigned long long)(w & 0xFFFFFFu));
            }
        }
    }
    __syncthreads();

    // writeout: thread = tok; every output written exactly once
    const int tok = threadIdx.x;
    #pragma unroll
    for (int c = 0; c < GACC; ++c) {
        const int b = b0 + c;
        const unsigned long long v = hist[(c << 8) | tok];
        const float cntf = (float)(uint32_t)(v >> 40);
        const float wts  = (float)(v & ((1ULL << 40) - 1)) * (1.0f / 16777216.0f);
        const int pos = b % 300;
        const int dp = b / 300;
        const int base0 = dp * 153600 + pos;
        out[base0 + tok * 300]         = cntf;   // c=0: count
        out[base0 + 76800 + tok * 300] = wts;    // c=1: wt sum
    }
}

// ---- fallback (ws too small / n out of range) ----
__global__ __launch_bounds__(TPB) void e2src_hist_atomic(const float4* __restrict__ x,
                                                         float* __restrict__ out, int n) {
    const float* xf = (const float*)x;
    const float t0 = xf[0];
    const float tlast = xf[(size_t)(n - 1) * 4];
    const float d_wt = tlast - t0 + 1e-4f;
    const float d_dt = tlast - t0 + 1.0f;
    int i = blockIdx.x * blockDim.x + threadIdx.x;
    const int stride = gridDim.x * blockDim.x;
    for (; i < n; i += stride) {
        float4 e = x[i];
        int bucket, tok; float wt;
        classify_full(e, t0, d_wt, d_dt, bucket, tok, wt);
        const int dp = bucket / 300, pos = bucket % 300;
        const int base = dp * 153600 + tok * 300 + pos;
        unsafeAtomicAdd(out + base, 1.0f);
        unsafeAtomicAdd(out + base + 76800, wt);
    }
}

extern "C" void kernel_launch(void* const* d_in, const int* in_sizes, int n_in,
                              void* d_out, int out_size, void* d_ws, size_t ws_size,
                              hipStream_t stream) {
    const float* x = (const float*)d_in[0];
    float* out = (float*)d_out;
    const int n = in_sizes[0] / 4;

    const size_t payload_bytes = (size_t)n * 4u;
    const size_t pfx_bytes = (size_t)B1 * NBUCKET * 2u;
    const size_t need = payload_bytes + pfx_bytes;    // 76.94 MB at n=2^24

    if (ws_size < need || n > B1 * CHUNK) {
        hipMemsetAsync(d_out, 0, (size_t)out_size * sizeof(float), stream);
        hipLaunchKernelGGL(e2src_hist_atomic, dim3(8192), dim3(TPB), 0, stream,
                           (const float4*)x, out, n);
        return;
    }

    uint32_t* payload = (uint32_t*)d_ws;
    uint16_t* pfx = (uint16_t*)((char*)d_ws + payload_bytes);

    hipLaunchKernelGGL(k_bin, dim3(B1), dim3(TPB), 0, stream,
                       (const float4*)x, payload, pfx, n);
    hipLaunchKernelGGL(k_accum, dim3(NACC), dim3(TPB), 0, stream,
                       payload, pfx, out, n);
    // k_accum writes every output exactly once -> no memset needed.
}